// Round 8
// baseline (387.105 us; speedup 1.0000x reference)
//
#include <hip/hip_runtime.h>
#include <hip/hip_bf16.h>

// GCNConv + ReLU: out = relu( (A_norm @ (x W)) + b ), A_norm = D^-1/2 (A + I) D^-1/2
// Round 8: keep slice-major phase-resident gather (r7: FETCH 352->131 MB, proven),
// remove r7's per-wave overhead (r7 ran 8x waves each paying prologue+butterfly:
// VALU 36->103 us). New aggregate: 8 nodes per wave, one per 8-lane group; a
// group's partial sum IS the node's sum (no cross-group reduce), every lane
// stores. Wave count back to 50K per slice-set. Cost: inner trip = max degree
// in group (~+30% masked work).
// Build (pass1 bucket-bin + pass2 LDS sort) and MFMA GEMM unchanged.

#define FEATS 256
#define MAXBUCK 200   // >= (50000+255)>>8 = 196
#define P1_CAP 64     // LDS slots per bucket per 4096-edge chunk (mean ~21)
#define BCAP 10240    // temp capacity per bucket (mean 8192, ~22 sigma)

typedef __bf16 bf16x8 __attribute__((ext_vector_type(8)));
typedef float f32x4 __attribute__((ext_vector_type(4)));

__device__ __forceinline__ unsigned short f2bf(float f) {  // RNE
  unsigned u = __float_as_uint(f);
  u += 0x7fffu + ((u >> 16) & 1u);
  return (unsigned short)(u >> 16);
}
__device__ __forceinline__ float bflo(unsigned u) { return __uint_as_float(u << 16); }
__device__ __forceinline__ float bfhi(unsigned u) { return __uint_as_float(u & 0xFFFF0000u); }

// ---------------- CSR build ----------------

__global__ __launch_bounds__(256) void zero_i32(int* __restrict__ p, int n) {
  int i = blockIdx.x * 256 + threadIdx.x;
  if (i < n) p[i] = 0;
}

// pass1: bin packed edges (dst<<16|src) by dst>>8. 1024 threads, 4096 edges/block.
__global__ __launch_bounds__(1024) void pass1_bin(const int* __restrict__ src,
                                                  const int* __restrict__ dst,
                                                  int E, int nbuck,
                                                  int* __restrict__ gcursor,
                                                  unsigned* __restrict__ temp) {
  __shared__ unsigned lbuf[MAXBUCK * P1_CAP];  // 51.2 KB
  __shared__ int lcnt[MAXBUCK];
  __shared__ int lbase[MAXBUCK];
  const int tid = threadIdx.x;
  for (int i = tid; i < nbuck; i += 1024) lcnt[i] = 0;
  __syncthreads();

  const int e0 = blockIdx.x * 4096;
  #pragma unroll
  for (int i = 0; i < 4; ++i) {
    int e = e0 + i * 1024 + tid;
    if (e < E) {
      unsigned d = (unsigned)dst[e];
      unsigned p = (d << 16) | (unsigned)src[e];
      int b = (int)(d >> 8);
      int pos = atomicAdd(&lcnt[b], 1);
      if (pos < P1_CAP) {
        lbuf[b * P1_CAP + pos] = p;
      } else {  // rare spill: direct global scatter
        int gp = atomicAdd(&gcursor[b], 1);
        temp[(size_t)b * BCAP + gp] = p;
      }
    }
  }
  __syncthreads();
  if (tid < nbuck) {
    int c = lcnt[tid]; if (c > P1_CAP) c = P1_CAP;
    lcnt[tid] = c;
    lbase[tid] = atomicAdd(&gcursor[tid], c);
  }
  __syncthreads();
  for (int i = tid; i < nbuck * P1_CAP; i += 1024) {
    int b = i >> 6, j = i & (P1_CAP - 1);
    if (j < lcnt[b]) temp[(size_t)b * BCAP + lbase[b] + j] = lbuf[i];
  }
}

// exclusive scan over bucket counts (nbuck <= 256), one block
__global__ __launch_bounds__(256) void scan_buckets(const int* __restrict__ gcursor,
                                                    int* __restrict__ bbase,
                                                    int* __restrict__ row_ptr,
                                                    int nbuck, int n) {
  __shared__ int tmp[256];
  int t = threadIdx.x;
  int v = (t < nbuck) ? min(gcursor[t], BCAP) : 0;
  tmp[t] = v;
  __syncthreads();
  #pragma unroll
  for (int off = 1; off < 256; off <<= 1) {
    int x = (t >= off) ? tmp[t - off] : 0;
    __syncthreads();
    tmp[t] += x;
    __syncthreads();
  }
  if (t < nbuck) bbase[t] = tmp[t] - v;
  if (t == 0) row_ptr[n] = tmp[255];
}

// pass2: per-bucket local CSR. 1024 threads.
__global__ __launch_bounds__(1024) void pass2_csr(const unsigned* __restrict__ temp,
                                                  const int* __restrict__ gcursor,
                                                  const int* __restrict__ bbase,
                                                  unsigned short* __restrict__ csr16,
                                                  int* __restrict__ row_ptr,
                                                  float* __restrict__ dinv, int n) {
  __shared__ unsigned ebuf[BCAP];          // 40 KB
  __shared__ unsigned short sorted[BCAP];  // 20 KB
  __shared__ int hist[256], scn[256], sexcl[256], ofs[256];
  const int b = blockIdx.x;
  const int tid = threadIdx.x;
  int cnt = gcursor[b]; if (cnt > BCAP) cnt = BCAP;
  const int base = bbase[b];
  const unsigned* tp = temp + (size_t)b * BCAP;

  if (tid < 256) { hist[tid] = 0; ofs[tid] = 0; }
  for (int i = tid; i < cnt; i += 1024) ebuf[i] = tp[i];
  __syncthreads();
  for (int i = tid; i < cnt; i += 1024) atomicAdd(&hist[(ebuf[i] >> 16) & 255], 1);
  __syncthreads();

  if (tid < 256) scn[tid] = hist[tid];
  __syncthreads();
  #pragma unroll
  for (int off = 1; off < 256; off <<= 1) {
    int x = 0;
    if (tid < 256 && tid >= off) x = scn[tid - off];
    __syncthreads();
    if (tid < 256) scn[tid] += x;
    __syncthreads();
  }
  if (tid < 256) {
    int v = hist[tid];
    int excl = scn[tid] - v;
    sexcl[tid] = excl;
    int node = (b << 8) + tid;
    if (node < n) {
      row_ptr[node] = base + excl;
      dinv[node] = rsqrtf((float)(v + 1));  // +1 self loop
    }
  }
  __syncthreads();

  for (int i = tid; i < cnt; i += 1024) {
    unsigned e = ebuf[i];
    int dl = (int)((e >> 16) & 255);
    int pos = sexcl[dl] + atomicAdd(&ofs[dl], 1);
    sorted[pos] = (unsigned short)(e & 0xFFFFu);
  }
  __syncthreads();
  for (int i = tid; i < cnt; i += 1024) csr16[base + i] = sorted[i];
}

// ---------------- W transpose + bf16 convert: Wt[n][k] = bf16(W[k][n]) ----------------

__global__ __launch_bounds__(256) void wt_build(const float* __restrict__ W,
                                                unsigned short* __restrict__ Wt) {
  int k = blockIdx.x;
  int nn = threadIdx.x;
  Wt[nn * FEATS + k] = f2bf(W[k * FEATS + nn]);
}

// ---------------- MFMA GEMM -> slice-major xwpS[slice][row][32] ----------------

__global__ __launch_bounds__(256) void gemm_mfma(const float* __restrict__ x,
                                                 const unsigned short* __restrict__ Wt,
                                                 const float* __restrict__ dinv,
                                                 unsigned short* __restrict__ xwpS, int M) {
  const int wave = (int)((blockIdx.x * 256 + threadIdx.x) >> 6);
  const int lane = (int)(threadIdx.x & 63);
  const int m0 = wave * 16;
  if (m0 >= M) return;
  const int lm = lane & 15;
  const int quad = lane >> 4;

  int arow = m0 + lm; if (arow >= M) arow = M - 1;
  const float* xrow = x + (size_t)arow * FEATS + quad * 8;
  bf16x8 Afrag[8];
  #pragma unroll
  for (int kc = 0; kc < 8; ++kc) {
    const float4 f0 = *(const float4*)(xrow + kc * 32);
    const float4 f1 = *(const float4*)(xrow + kc * 32 + 4);
    union { bf16x8 v; unsigned short u[8]; } a;
    a.u[0] = f2bf(f0.x); a.u[1] = f2bf(f0.y); a.u[2] = f2bf(f0.z); a.u[3] = f2bf(f0.w);
    a.u[4] = f2bf(f1.x); a.u[5] = f2bf(f1.y); a.u[6] = f2bf(f1.z); a.u[7] = f2bf(f1.w);
    Afrag[kc] = a.v;
  }

  float dsc[4];
  #pragma unroll
  for (int r = 0; r < 4; ++r) {
    int rr = m0 + quad * 4 + r; if (rr >= M) rr = M - 1;
    dsc[r] = dinv[rr];
  }

  for (int ct = 0; ct < 16; ++ct) {
    const int c0 = ct * 16;
    const unsigned short* wrow = Wt + (size_t)(c0 + lm) * FEATS + quad * 8;
    f32x4 acc = {0.f, 0.f, 0.f, 0.f};
    #pragma unroll
    for (int kc = 0; kc < 8; ++kc) {
      bf16x8 B = *(const bf16x8*)(wrow + kc * 32);
      acc = __builtin_amdgcn_mfma_f32_16x16x32_bf16(Afrag[kc], B, acc, 0, 0, 0);
    }
    // slice-major store: slice = ct>>1, within-slice col = (ct&1)*16 + lm
    unsigned short* sl = xwpS + ((size_t)(ct >> 1) * M) * 32 + (ct & 1) * 16 + lm;
    #pragma unroll
    for (int r = 0; r < 4; ++r) {
      int row = m0 + quad * 4 + r;
      if (row < M) sl[(size_t)row * 32] = f2bf(acc[r] * dsc[r]);
    }
  }
}

// ---------------- aggregation: phase-resident slices, 8 nodes/wave ----------------
// slice = blockIdx / bps (grid-major phases; correctness order-independent).
// Wave = 8 nodes x 1 slice: group g (lanes 8g..8g+7) owns node base+g; lane's
// uint2 (4 bf16) covers cols cl*4..cl*4+3 of the 32-col slice. Group partial
// IS the node sum -- no butterfly, dense epilogue. 4-deep unrolled gather.

__global__ __launch_bounds__(256) void aggregate_s(const unsigned short* __restrict__ xwpS,
                                                   const float* __restrict__ dinv,
                                                   const int* __restrict__ row_ptr,
                                                   const unsigned short* __restrict__ csr16,
                                                   const float* __restrict__ bias,
                                                   float* __restrict__ out, int n, int bps) {
  const int slice = (int)(blockIdx.x / (unsigned)bps);
  const int wid = (int)((blockIdx.x % (unsigned)bps) * 4 + (threadIdx.x >> 6));
  const int lane = (int)(threadIdx.x & 63);
  const int g = lane >> 3;     // node group 0..7
  const int cl = lane & 7;     // col lane 0..7 (uint2 each)
  const int node = wid * 8 + g;
  if (node >= n) return;
  const unsigned short* sl = xwpS + ((size_t)slice * n) * 32;

  // self-loop init (xwpS prescaled by dinv[src])
  uint2 sv = *(const uint2*)(sl + (size_t)node * 32 + cl * 4);
  float a0 = bflo(sv.x), a1 = bfhi(sv.x), a2 = bflo(sv.y), a3 = bfhi(sv.y);

  const int beg = row_ptr[node];
  const int end = row_ptr[node + 1];
  for (int i = beg; i < end; i += 4) {
    int e0, e1, e2, e3;
    e0 = (int)__builtin_nontemporal_load(csr16 + i);
    e1 = (int)__builtin_nontemporal_load(csr16 + min(i + 1, end - 1));
    e2 = (int)__builtin_nontemporal_load(csr16 + min(i + 2, end - 1));
    e3 = (int)__builtin_nontemporal_load(csr16 + min(i + 3, end - 1));
    uint2 v0 = *(const uint2*)(sl + (size_t)e0 * 32 + cl * 4);
    uint2 v1 = *(const uint2*)(sl + (size_t)e1 * 32 + cl * 4);
    uint2 v2 = *(const uint2*)(sl + (size_t)e2 * 32 + cl * 4);
    uint2 v3 = *(const uint2*)(sl + (size_t)e3 * 32 + cl * 4);
    a0 += bflo(v0.x); a1 += bfhi(v0.x); a2 += bflo(v0.y); a3 += bfhi(v0.y);
    if (i + 1 < end) { a0 += bflo(v1.x); a1 += bfhi(v1.x); a2 += bflo(v1.y); a3 += bfhi(v1.y); }
    if (i + 2 < end) { a0 += bflo(v2.x); a1 += bfhi(v2.x); a2 += bflo(v2.y); a3 += bfhi(v2.y); }
    if (i + 3 < end) { a0 += bflo(v3.x); a1 += bfhi(v3.x); a2 += bflo(v3.y); a3 += bfhi(v3.y); }
  }

  const float dd = dinv[node];
  const float* bp = bias + slice * 32 + cl * 4;
  f32x4 o;
  o.x = fmaxf(fmaf(a0, dd, bp[0]), 0.f);
  o.y = fmaxf(fmaf(a1, dd, bp[1]), 0.f);
  o.z = fmaxf(fmaf(a2, dd, bp[2]), 0.f);
  o.w = fmaxf(fmaf(a3, dd, bp[3]), 0.f);
  __builtin_nontemporal_store(o, (f32x4*)(out + (size_t)node * FEATS + slice * 32 + cl * 4));
}

// ---------------- launch ----------------

extern "C" void kernel_launch(void* const* d_in, const int* in_sizes, int n_in,
                              void* d_out, int out_size, void* d_ws, size_t ws_size,
                              hipStream_t stream) {
  const float* x  = (const float*)d_in[0];   // [n, 256]
  const int*   ei = (const int*)d_in[1];     // [2, E]
  const float* W  = (const float*)d_in[2];   // [256, 256]
  const float* b  = (const float*)d_in[3];   // [256]

  const int n = in_sizes[0] / FEATS;         // 50000
  const int E = in_sizes[1] / 2;             // 1,600,000
  const int* src = ei;
  const int* dst = ei + E;
  const int nbuck = (n + 255) >> 8;          // 196

  // workspace layout (bytes)
  char* ws = (char*)d_ws;
  unsigned short* xwpS  = (unsigned short*)(ws);                 // 25,600,000 (8 slices x n x 32)
  unsigned short* Wt    = (unsigned short*)(ws + 25600000);      //    131,072
  float*          dinv  = (float*)(ws + 25731072);               //    200,000
  int*            row_ptr = (int*)(ws + 25931072);               //    200,064
  unsigned short* csr16 = (unsigned short*)(ws + 26131136);      //  3,200,000
  int*            gcursor = (int*)(ws + 29331136);               //      1,024
  int*            bbase   = (int*)(ws + 29332160);               //      1,024
  unsigned*       temp    = (unsigned*)(ws + 29333184);          //  8,028,160
  // total ~37.4 MB

  hipLaunchKernelGGL(zero_i32, dim3(1), dim3(256), 0, stream, gcursor, nbuck);
  hipLaunchKernelGGL(wt_build, dim3(256), dim3(256), 0, stream, W, Wt);

  const int g_p1 = (E + 4095) / 4096;  // 391
  hipLaunchKernelGGL(pass1_bin, dim3(g_p1), dim3(1024), 0, stream, src, dst, E, nbuck, gcursor, temp);
  hipLaunchKernelGGL(scan_buckets, dim3(1), dim3(256), 0, stream, gcursor, bbase, row_ptr, nbuck, n);
  hipLaunchKernelGGL(pass2_csr, dim3(nbuck), dim3(1024), 0, stream, temp, gcursor, bbase,
                     csr16, row_ptr, dinv, n);

  const int strips = (n + 15) / 16;
  hipLaunchKernelGGL(gemm_mfma, dim3((strips + 3) / 4), dim3(256), 0, stream, x, Wt, dinv, xwpS, n);

  const int wps = (n + 7) / 8;          // waves per slice (8 nodes/wave)
  const int bps = (wps + 3) / 4;        // blocks per slice (4 waves/block)
  hipLaunchKernelGGL(aggregate_s, dim3(bps * 8), dim3(256), 0, stream,
                     xwpS, dinv, row_ptr, csr16, b, (float*)d_out, n, bps);
}

// Round 9
// 297.425 us; speedup vs baseline: 1.3015x; 1.3015x over previous
//
#include <hip/hip_runtime.h>
#include <hip/hip_bf16.h>

// GCNConv + ReLU: out = relu( (A_norm @ (x W)) + b ), A_norm = D^-1/2 (A + I) D^-1/2
// Round 9: r8's low-overhead group aggregate + LDS-staged edge lists.
//   r8 regressed because each 8-lane group NT-loaded its own csr16 stream:
//   uncoalesced NT = no L2 dedup, 16x overfetch (FETCH 131->440 MB). csr16 is
//   dst-sorted, so a block's 32 consecutive nodes own a contiguous edge range:
//   stage it into LDS with coalesced NT loads (csr16 traffic back to 25.6 MB),
//   groups read edge IDs from LDS (broadcast, conflict-free).
// Slice-major phase-resident xwpS gather (r7-proven), 8 nodes/wave, no
// butterfly, dense epilogue. Build + MFMA GEMM unchanged.

#define FEATS 256
#define MAXBUCK 200   // >= (50000+255)>>8 = 196
#define P1_CAP 64     // LDS slots per bucket per 4096-edge chunk (mean ~21)
#define BCAP 10240    // temp capacity per bucket (mean 8192, ~22 sigma)
#define ECAP 4096     // aggregate: LDS edge-stage capacity (mean block load ~1024)

typedef __bf16 bf16x8 __attribute__((ext_vector_type(8)));
typedef float f32x4 __attribute__((ext_vector_type(4)));

__device__ __forceinline__ unsigned short f2bf(float f) {  // RNE
  unsigned u = __float_as_uint(f);
  u += 0x7fffu + ((u >> 16) & 1u);
  return (unsigned short)(u >> 16);
}
__device__ __forceinline__ float bflo(unsigned u) { return __uint_as_float(u << 16); }
__device__ __forceinline__ float bfhi(unsigned u) { return __uint_as_float(u & 0xFFFF0000u); }

// ---------------- CSR build ----------------

__global__ __launch_bounds__(256) void zero_i32(int* __restrict__ p, int n) {
  int i = blockIdx.x * 256 + threadIdx.x;
  if (i < n) p[i] = 0;
}

// pass1: bin packed edges (dst<<16|src) by dst>>8. 1024 threads, 4096 edges/block.
__global__ __launch_bounds__(1024) void pass1_bin(const int* __restrict__ src,
                                                  const int* __restrict__ dst,
                                                  int E, int nbuck,
                                                  int* __restrict__ gcursor,
                                                  unsigned* __restrict__ temp) {
  __shared__ unsigned lbuf[MAXBUCK * P1_CAP];  // 51.2 KB
  __shared__ int lcnt[MAXBUCK];
  __shared__ int lbase[MAXBUCK];
  const int tid = threadIdx.x;
  for (int i = tid; i < nbuck; i += 1024) lcnt[i] = 0;
  __syncthreads();

  const int e0 = blockIdx.x * 4096;
  #pragma unroll
  for (int i = 0; i < 4; ++i) {
    int e = e0 + i * 1024 + tid;
    if (e < E) {
      unsigned d = (unsigned)dst[e];
      unsigned p = (d << 16) | (unsigned)src[e];
      int b = (int)(d >> 8);
      int pos = atomicAdd(&lcnt[b], 1);
      if (pos < P1_CAP) {
        lbuf[b * P1_CAP + pos] = p;
      } else {  // rare spill: direct global scatter
        int gp = atomicAdd(&gcursor[b], 1);
        temp[(size_t)b * BCAP + gp] = p;
      }
    }
  }
  __syncthreads();
  if (tid < nbuck) {
    int c = lcnt[tid]; if (c > P1_CAP) c = P1_CAP;
    lcnt[tid] = c;
    lbase[tid] = atomicAdd(&gcursor[tid], c);
  }
  __syncthreads();
  for (int i = tid; i < nbuck * P1_CAP; i += 1024) {
    int b = i >> 6, j = i & (P1_CAP - 1);
    if (j < lcnt[b]) temp[(size_t)b * BCAP + lbase[b] + j] = lbuf[i];
  }
}

// exclusive scan over bucket counts (nbuck <= 256), one block
__global__ __launch_bounds__(256) void scan_buckets(const int* __restrict__ gcursor,
                                                    int* __restrict__ bbase,
                                                    int* __restrict__ row_ptr,
                                                    int nbuck, int n) {
  __shared__ int tmp[256];
  int t = threadIdx.x;
  int v = (t < nbuck) ? min(gcursor[t], BCAP) : 0;
  tmp[t] = v;
  __syncthreads();
  #pragma unroll
  for (int off = 1; off < 256; off <<= 1) {
    int x = (t >= off) ? tmp[t - off] : 0;
    __syncthreads();
    tmp[t] += x;
    __syncthreads();
  }
  if (t < nbuck) bbase[t] = tmp[t] - v;
  if (t == 0) row_ptr[n] = tmp[255];
}

// pass2: per-bucket local CSR. 1024 threads.
__global__ __launch_bounds__(1024) void pass2_csr(const unsigned* __restrict__ temp,
                                                  const int* __restrict__ gcursor,
                                                  const int* __restrict__ bbase,
                                                  unsigned short* __restrict__ csr16,
                                                  int* __restrict__ row_ptr,
                                                  float* __restrict__ dinv, int n) {
  __shared__ unsigned ebuf[BCAP];          // 40 KB
  __shared__ unsigned short sorted[BCAP];  // 20 KB
  __shared__ int hist[256], scn[256], sexcl[256], ofs[256];
  const int b = blockIdx.x;
  const int tid = threadIdx.x;
  int cnt = gcursor[b]; if (cnt > BCAP) cnt = BCAP;
  const int base = bbase[b];
  const unsigned* tp = temp + (size_t)b * BCAP;

  if (tid < 256) { hist[tid] = 0; ofs[tid] = 0; }
  for (int i = tid; i < cnt; i += 1024) ebuf[i] = tp[i];
  __syncthreads();
  for (int i = tid; i < cnt; i += 1024) atomicAdd(&hist[(ebuf[i] >> 16) & 255], 1);
  __syncthreads();

  if (tid < 256) scn[tid] = hist[tid];
  __syncthreads();
  #pragma unroll
  for (int off = 1; off < 256; off <<= 1) {
    int x = 0;
    if (tid < 256 && tid >= off) x = scn[tid - off];
    __syncthreads();
    if (tid < 256) scn[tid] += x;
    __syncthreads();
  }
  if (tid < 256) {
    int v = hist[tid];
    int excl = scn[tid] - v;
    sexcl[tid] = excl;
    int node = (b << 8) + tid;
    if (node < n) {
      row_ptr[node] = base + excl;
      dinv[node] = rsqrtf((float)(v + 1));  // +1 self loop
    }
  }
  __syncthreads();

  for (int i = tid; i < cnt; i += 1024) {
    unsigned e = ebuf[i];
    int dl = (int)((e >> 16) & 255);
    int pos = sexcl[dl] + atomicAdd(&ofs[dl], 1);
    sorted[pos] = (unsigned short)(e & 0xFFFFu);
  }
  __syncthreads();
  for (int i = tid; i < cnt; i += 1024) csr16[base + i] = sorted[i];
}

// ---------------- W transpose + bf16 convert: Wt[n][k] = bf16(W[k][n]) ----------------

__global__ __launch_bounds__(256) void wt_build(const float* __restrict__ W,
                                                unsigned short* __restrict__ Wt) {
  int k = blockIdx.x;
  int nn = threadIdx.x;
  Wt[nn * FEATS + k] = f2bf(W[k * FEATS + nn]);
}

// ---------------- MFMA GEMM -> slice-major xwpS[slice][row][32] ----------------

__global__ __launch_bounds__(256) void gemm_mfma(const float* __restrict__ x,
                                                 const unsigned short* __restrict__ Wt,
                                                 const float* __restrict__ dinv,
                                                 unsigned short* __restrict__ xwpS, int M) {
  const int wave = (int)((blockIdx.x * 256 + threadIdx.x) >> 6);
  const int lane = (int)(threadIdx.x & 63);
  const int m0 = wave * 16;
  if (m0 >= M) return;
  const int lm = lane & 15;
  const int quad = lane >> 4;

  int arow = m0 + lm; if (arow >= M) arow = M - 1;
  const float* xrow = x + (size_t)arow * FEATS + quad * 8;
  bf16x8 Afrag[8];
  #pragma unroll
  for (int kc = 0; kc < 8; ++kc) {
    const float4 f0 = *(const float4*)(xrow + kc * 32);
    const float4 f1 = *(const float4*)(xrow + kc * 32 + 4);
    union { bf16x8 v; unsigned short u[8]; } a;
    a.u[0] = f2bf(f0.x); a.u[1] = f2bf(f0.y); a.u[2] = f2bf(f0.z); a.u[3] = f2bf(f0.w);
    a.u[4] = f2bf(f1.x); a.u[5] = f2bf(f1.y); a.u[6] = f2bf(f1.z); a.u[7] = f2bf(f1.w);
    Afrag[kc] = a.v;
  }

  float dsc[4];
  #pragma unroll
  for (int r = 0; r < 4; ++r) {
    int rr = m0 + quad * 4 + r; if (rr >= M) rr = M - 1;
    dsc[r] = dinv[rr];
  }

  for (int ct = 0; ct < 16; ++ct) {
    const int c0 = ct * 16;
    const unsigned short* wrow = Wt + (size_t)(c0 + lm) * FEATS + quad * 8;
    f32x4 acc = {0.f, 0.f, 0.f, 0.f};
    #pragma unroll
    for (int kc = 0; kc < 8; ++kc) {
      bf16x8 B = *(const bf16x8*)(wrow + kc * 32);
      acc = __builtin_amdgcn_mfma_f32_16x16x32_bf16(Afrag[kc], B, acc, 0, 0, 0);
    }
    // slice-major store: slice = ct>>1, within-slice col = (ct&1)*16 + lm
    unsigned short* sl = xwpS + ((size_t)(ct >> 1) * M) * 32 + (ct & 1) * 16 + lm;
    #pragma unroll
    for (int r = 0; r < 4; ++r) {
      int row = m0 + quad * 4 + r;
      if (row < M) sl[(size_t)row * 32] = f2bf(acc[r] * dsc[r]);
    }
  }
}

// ---------------- aggregation: phase-resident slices, 8 nodes/wave, LDS edges ----------
// slice = blockIdx / bps. Block = 32 consecutive nodes (4 waves x 8 groups).
// csr16 is dst-sorted -> block's edge range is contiguous: stage into LDS with
// coalesced NT loads (chunk loop for safety), groups read IDs from LDS.

__global__ __launch_bounds__(256) void aggregate_s(const unsigned short* __restrict__ xwpS,
                                                   const float* __restrict__ dinv,
                                                   const int* __restrict__ row_ptr,
                                                   const unsigned short* __restrict__ csr16,
                                                   const float* __restrict__ bias,
                                                   float* __restrict__ out, int n, int bps) {
  __shared__ unsigned short lds_e[ECAP];  // 8 KB
  const int slice = (int)(blockIdx.x / (unsigned)bps);
  const int nb0 = (int)(blockIdx.x % (unsigned)bps) * 32;  // first node of block (< n)
  const int tid = (int)threadIdx.x;
  const int lane = tid & 63;
  const int g = lane >> 3;     // node group 0..7
  const int cl = lane & 7;     // col lane 0..7 (uint2 each)
  const int node = nb0 + (tid >> 6) * 8 + g;
  const bool valid = node < n;
  const unsigned short* sl = xwpS + ((size_t)slice * n) * 32;

  float a0 = 0.f, a1 = 0.f, a2 = 0.f, a3 = 0.f;
  if (valid) {  // self-loop init (xwpS prescaled by dinv[src])
    uint2 sv = *(const uint2*)(sl + (size_t)node * 32 + cl * 4);
    a0 = bflo(sv.x); a1 = bfhi(sv.x); a2 = bflo(sv.y); a3 = bfhi(sv.y);
  }

  const int beg = valid ? row_ptr[node] : 0;
  const int end = valid ? row_ptr[node + 1] : 0;
  const int ebeg = row_ptr[nb0];                 // block-uniform
  const int eend = row_ptr[min(nb0 + 32, n)];    // block-uniform

  for (int cb = ebeg; cb < eend; cb += ECAP) {   // nearly always 1 iteration
    const int cnt = min(ECAP, eend - cb);
    __syncthreads();
    for (int i = tid; i < cnt; i += 256)
      lds_e[i] = __builtin_nontemporal_load(csr16 + cb + i);
    __syncthreads();
    const int clo = max(beg, cb);
    const int chi = min(end, cb + cnt);
    const int last = chi - 1;
    for (int i = clo; i < chi; i += 4) {
      int e0 = (int)lds_e[i - cb];
      int e1 = (int)lds_e[min(i + 1, last) - cb];
      int e2 = (int)lds_e[min(i + 2, last) - cb];
      int e3 = (int)lds_e[min(i + 3, last) - cb];
      uint2 v0 = *(const uint2*)(sl + (size_t)e0 * 32 + cl * 4);
      uint2 v1 = *(const uint2*)(sl + (size_t)e1 * 32 + cl * 4);
      uint2 v2 = *(const uint2*)(sl + (size_t)e2 * 32 + cl * 4);
      uint2 v3 = *(const uint2*)(sl + (size_t)e3 * 32 + cl * 4);
      a0 += bflo(v0.x); a1 += bfhi(v0.x); a2 += bflo(v0.y); a3 += bfhi(v0.y);
      if (i + 1 < chi) { a0 += bflo(v1.x); a1 += bfhi(v1.x); a2 += bflo(v1.y); a3 += bfhi(v1.y); }
      if (i + 2 < chi) { a0 += bflo(v2.x); a1 += bfhi(v2.x); a2 += bflo(v2.y); a3 += bfhi(v2.y); }
      if (i + 3 < chi) { a0 += bflo(v3.x); a1 += bfhi(v3.x); a2 += bflo(v3.y); a3 += bfhi(v3.y); }
    }
  }

  if (valid) {
    const float dd = dinv[node];
    const float* bp = bias + slice * 32 + cl * 4;
    f32x4 o;
    o.x = fmaxf(fmaf(a0, dd, bp[0]), 0.f);
    o.y = fmaxf(fmaf(a1, dd, bp[1]), 0.f);
    o.z = fmaxf(fmaf(a2, dd, bp[2]), 0.f);
    o.w = fmaxf(fmaf(a3, dd, bp[3]), 0.f);
    __builtin_nontemporal_store(o, (f32x4*)(out + (size_t)node * FEATS + slice * 32 + cl * 4));
  }
}

// ---------------- launch ----------------

extern "C" void kernel_launch(void* const* d_in, const int* in_sizes, int n_in,
                              void* d_out, int out_size, void* d_ws, size_t ws_size,
                              hipStream_t stream) {
  const float* x  = (const float*)d_in[0];   // [n, 256]
  const int*   ei = (const int*)d_in[1];     // [2, E]
  const float* W  = (const float*)d_in[2];   // [256, 256]
  const float* b  = (const float*)d_in[3];   // [256]

  const int n = in_sizes[0] / FEATS;         // 50000
  const int E = in_sizes[1] / 2;             // 1,600,000
  const int* src = ei;
  const int* dst = ei + E;
  const int nbuck = (n + 255) >> 8;          // 196

  // workspace layout (bytes)
  char* ws = (char*)d_ws;
  unsigned short* xwpS  = (unsigned short*)(ws);                 // 25,600,000 (8 slices x n x 32)
  unsigned short* Wt    = (unsigned short*)(ws + 25600000);      //    131,072
  float*          dinv  = (float*)(ws + 25731072);               //    200,000
  int*            row_ptr = (int*)(ws + 25931072);               //    200,064
  unsigned short* csr16 = (unsigned short*)(ws + 26131136);      //  3,200,000
  int*            gcursor = (int*)(ws + 29331136);               //      1,024
  int*            bbase   = (int*)(ws + 29332160);               //      1,024
  unsigned*       temp    = (unsigned*)(ws + 29333184);          //  8,028,160
  // total ~37.4 MB

  hipLaunchKernelGGL(zero_i32, dim3(1), dim3(256), 0, stream, gcursor, nbuck);
  hipLaunchKernelGGL(wt_build, dim3(256), dim3(256), 0, stream, W, Wt);

  const int g_p1 = (E + 4095) / 4096;  // 391
  hipLaunchKernelGGL(pass1_bin, dim3(g_p1), dim3(1024), 0, stream, src, dst, E, nbuck, gcursor, temp);
  hipLaunchKernelGGL(scan_buckets, dim3(1), dim3(256), 0, stream, gcursor, bbase, row_ptr, nbuck, n);
  hipLaunchKernelGGL(pass2_csr, dim3(nbuck), dim3(1024), 0, stream, temp, gcursor, bbase,
                     csr16, row_ptr, dinv, n);

  const int strips = (n + 15) / 16;
  hipLaunchKernelGGL(gemm_mfma, dim3((strips + 3) / 4), dim3(256), 0, stream, x, Wt, dinv, xwpS, n);

  const int bps = (n + 31) / 32;        // blocks per slice (32 nodes/block)
  hipLaunchKernelGGL(aggregate_s, dim3(bps * 8), dim3(256), 0, stream,
                     xwpS, dinv, row_ptr, csr16, b, (float*)d_out, n, bps);
}